// Round 2
// baseline (1433.521 us; speedup 1.0000x reference)
//
#include <hip/hip_runtime.h>
#include <math.h>

typedef _Float16 f16;
typedef _Float16 f16x4 __attribute__((ext_vector_type(4)));
typedef _Float16 f16x8 __attribute__((ext_vector_type(8)));
typedef float f32x4 __attribute__((ext_vector_type(4)));

#define SEQ   2048
#define DIM   1024
#define NH    16
#define DH    64
#define NCOLS 6144
#define NHSD  (NH*SEQ*DH)   /* 2,097,152 elements per qkv sub-tensor */

// ---------------- cast x (fp32 -> f16), vectorized x4 ----------------
__global__ __launch_bounds__(256) void k_cast_x(const float* __restrict__ x, f16* __restrict__ xh) {
  int i = (blockIdx.x * 256 + threadIdx.x) * 4;
  float4 v = *(const float4*)(x + i);
  f16x4 h; h[0] = (f16)v.x; h[1] = (f16)v.y; h[2] = (f16)v.z; h[3] = (f16)v.w;
  *(f16x4*)(xh + i) = h;
}

// ------------- transpose + cast: out[c][r] = (f16) in[r][c], in is R x C -------------
__global__ __launch_bounds__(256) void k_tcast(const float* __restrict__ in, f16* __restrict__ out,
                                               int R, int C) {
  __shared__ f16 t[64 * 66];
  int bc = blockIdx.x, br = blockIdx.y;
  for (int it = 0; it < 16; ++it) {
    int idx = it * 256 + threadIdx.x;
    int r = idx >> 6, c = idx & 63;
    t[r * 66 + c] = (f16)in[(size_t)(br * 64 + r) * C + bc * 64 + c];
  }
  __syncthreads();
  for (int it = 0; it < 16; ++it) {
    int idx = it * 256 + threadIdx.x;
    int oc = idx >> 6, orr = idx & 63;
    out[(size_t)(bc * 64 + oc) * R + br * 64 + orr] = t[orr * 66 + oc];
  }
}

// ---------------- qkv GEMM: xh[2048,1024] @ WqT[6144,1024]^T -> six packed tensors ----------------
__global__ __launch_bounds__(256) void k_gemm_qkv(const f16* __restrict__ A, const f16* __restrict__ B,
                                                  f16* __restrict__ q6) {
  __shared__ f16 sa[128 * 72];
  __shared__ f16 sb[128 * 72];
  int bx = blockIdx.x, by = blockIdx.y;
  int tid = threadIdx.x, w = tid >> 6, l = tid & 63, q = l >> 4, c = l & 15;
  f32x4 acc[2][8];
  const f32x4 zf = {0.f, 0.f, 0.f, 0.f};
  for (int i = 0; i < 2; ++i) for (int j = 0; j < 8; ++j) acc[i][j] = zf;

  for (int kt = 0; kt < DIM / 64; ++kt) {
    __syncthreads();
#pragma unroll
    for (int it = 0; it < 4; ++it) {
      int idx = it * 256 + tid; int r = idx >> 3, ch = idx & 7;
      *(float4*)(sa + r * 72 + ch * 8) = *(const float4*)(A + (size_t)(by * 128 + r) * DIM + kt * 64 + ch * 8);
      *(float4*)(sb + r * 72 + ch * 8) = *(const float4*)(B + (size_t)(bx * 128 + r) * DIM + kt * 64 + ch * 8);
    }
    __syncthreads();
#pragma unroll
    for (int ks = 0; ks < 2; ++ks) {
      f16x8 af[2], bf[8];
#pragma unroll
      for (int tr = 0; tr < 2; ++tr) af[tr] = *(const f16x8*)(sa + (w * 32 + tr * 16 + c) * 72 + ks * 32 + q * 8);
#pragma unroll
      for (int tc = 0; tc < 8; ++tc) bf[tc] = *(const f16x8*)(sb + (tc * 16 + c) * 72 + ks * 32 + q * 8);
#pragma unroll
      for (int tr = 0; tr < 2; ++tr)
#pragma unroll
        for (int tc = 0; tc < 8; ++tc)
          acc[tr][tc] = __builtin_amdgcn_mfma_f32_16x16x32_f16(af[tr], bf[tc], acc[tr][tc], 0, 0, 0);
    }
  }
  // epilogue: scatter into qu(0) ku(1) vu(2) qc(3) kc(4) vcT(5); scale qu,qc by dh^-0.5
#pragma unroll
  for (int tr = 0; tr < 2; ++tr)
#pragma unroll
    for (int tc = 0; tc < 8; ++tc)
#pragma unroll
      for (int r = 0; r < 4; ++r) {
        int row = by * 128 + w * 32 + tr * 16 + q * 4 + r;
        int col = bx * 128 + tc * 16 + c;
        float v = acc[tr][tc][r];
        int t = col >> 10, head = (col >> 6) & 15, dh = col & 63;
        if (t == 0 || t == 3) v *= 0.125f;
        if (t == 5) q6[(size_t)5 * NHSD + (size_t)(head * DH + dh) * SEQ + row] = (f16)v;
        else        q6[(size_t)t * NHSD + (size_t)(head * SEQ + row) * DH + dh] = (f16)v;
      }
}

// ---------------- fused: on-the-fly term1/lookahead tiles + Su + Sc + silu + softmax + PV ----------------
// grid 256 = head (low 4 bits) x i-block I. 4 waves x 32 rows. LDS = sa(32K, A-side: t1 / P) + sb(32K, B-side: lk).
// LDS discipline: sa is written/read by OWN-wave rows only (no barrier); sb is read across waves
// (barrier before write = WAR vs prior Su-MFMA, barrier after write = RAW).
__global__ __launch_bounds__(256, 1) void k_flash(const f16* __restrict__ q6, f16* __restrict__ oh) {
  __shared__ f16 sa[128 * 128];
  __shared__ f16 sb[128 * 128];
  int head = blockIdx.x & 15, I = blockIdx.x >> 4;
  const f16* qu = q6 + (size_t)0 * NHSD + (size_t)head * SEQ * DH;   // pre-scaled by dh^-0.5
  const f16* ku = q6 + (size_t)1 * NHSD + (size_t)head * SEQ * DH;
  const f16* vu = q6 + (size_t)2 * NHSD + (size_t)head * SEQ * DH;
  const f16* qc = q6 + (size_t)3 * NHSD + (size_t)head * SEQ * DH;   // pre-scaled by dh^-0.5
  const f16* kc = q6 + (size_t)4 * NHSD + (size_t)head * SEQ * DH;
  const f16* vt = q6 + (size_t)5 * NHSD + (size_t)head * DH * SEQ;   // vc transposed [64][2048]
  int tid = threadIdx.x, w = tid >> 6, l = tid & 63, q = l >> 4, c = l & 15;

  // qc_s A-frags of this I-block: used for every t1 tile AND the Sc MFMA — hoist.
  f16x8 a_qc[2][2];
#pragma unroll
  for (int tr = 0; tr < 2; ++tr)
#pragma unroll
    for (int ks = 0; ks < 2; ++ks)
      a_qc[tr][ks] = *(const f16x8*)(qc + (size_t)(I * 128 + w * 32 + tr * 16 + c) * DH + ks * 32 + q * 8);

  f32x4 su[2][8], tacc[2][8], oacc[2][4];
  float m_i[2][4], l_i[2][4];
  const f32x4 zf = {0.f, 0.f, 0.f, 0.f};
  for (int tr = 0; tr < 2; ++tr) for (int tv = 0; tv < 4; ++tv) oacc[tr][tv] = zf;
  for (int tr = 0; tr < 2; ++tr) for (int r = 0; r < 4; ++r) { m_i[tr][r] = -INFINITY; l_i[tr][r] = 0.f; }

  for (int K = 0; K <= I; ++K) {
    // qu_s A-frags for the K-block (A-operand of the lk tile computes)
    f16x8 a_qu[2][2];
#pragma unroll
    for (int tr = 0; tr < 2; ++tr)
#pragma unroll
      for (int ks = 0; ks < 2; ++ks)
        a_qu[tr][ks] = *(const f16x8*)(qu + (size_t)(K * 128 + w * 32 + tr * 16 + c) * DH + ks * 32 + q * 8);

    for (int tr = 0; tr < 2; ++tr) for (int tc = 0; tc < 8; ++tc) su[tr][tc] = zf;

    for (int J = K; J <= I; ++J) {
      __syncthreads();   // WAR: prior Su-MFMA reads of sb complete before restaging

      // ---- lookahead(K,J) tile: sigmoid(qu_s(K) @ ku(J)^T), mask j>k -> sb (own k-rows) ----
      for (int tr = 0; tr < 2; ++tr) for (int tc = 0; tc < 8; ++tc) tacc[tr][tc] = zf;
#pragma unroll
      for (int ks = 0; ks < 2; ++ks) {
        f16x8 bf[8];
#pragma unroll
        for (int tc = 0; tc < 8; ++tc)
          bf[tc] = *(const f16x8*)(ku + (size_t)(J * 128 + tc * 16 + c) * DH + ks * 32 + q * 8);
#pragma unroll
        for (int tr = 0; tr < 2; ++tr)
#pragma unroll
          for (int tc = 0; tc < 8; ++tc)
            tacc[tr][tc] = __builtin_amdgcn_mfma_f32_16x16x32_f16(a_qu[tr][ks], bf[tc], tacc[tr][tc], 0, 0, 0);
      }
#pragma unroll
      for (int tr = 0; tr < 2; ++tr)
#pragma unroll
        for (int tc = 0; tc < 8; ++tc)
#pragma unroll
          for (int r = 0; r < 4; ++r) {
            int row = w * 32 + tr * 16 + q * 4 + r;
            int col = tc * 16 + c;
            int kg = K * 128 + row, jg = J * 128 + col;
            float v = tacc[tr][tc][r];
            f16 ov = (jg > kg) ? (f16)(1.f / (1.f + __expf(-v))) : (f16)(0.f);
            sb[(row << 7) + (((col >> 3) ^ (row & 15)) << 3) + (col & 7)] = ov;
          }

      // ---- term1(I,J) tile: qc_s(I) @ vu(J)^T, mask j<=i -> sa (own i-rows) ----
      for (int tr = 0; tr < 2; ++tr) for (int tc = 0; tc < 8; ++tc) tacc[tr][tc] = zf;
#pragma unroll
      for (int ks = 0; ks < 2; ++ks) {
        f16x8 bf[8];
#pragma unroll
        for (int tc = 0; tc < 8; ++tc)
          bf[tc] = *(const f16x8*)(vu + (size_t)(J * 128 + tc * 16 + c) * DH + ks * 32 + q * 8);
#pragma unroll
        for (int tr = 0; tr < 2; ++tr)
#pragma unroll
          for (int tc = 0; tc < 8; ++tc)
            tacc[tr][tc] = __builtin_amdgcn_mfma_f32_16x16x32_f16(a_qc[tr][ks], bf[tc], tacc[tr][tc], 0, 0, 0);
      }
#pragma unroll
      for (int tr = 0; tr < 2; ++tr)
#pragma unroll
        for (int tc = 0; tc < 8; ++tc)
#pragma unroll
          for (int r = 0; r < 4; ++r) {
            int row = w * 32 + tr * 16 + q * 4 + r;
            int col = tc * 16 + c;
            int ig = I * 128 + row, jg = J * 128 + col;
            float v = tacc[tr][tc][r];
            f16 ov = (jg <= ig) ? (f16)v : (f16)(0.f);
            sa[(row << 7) + (((col >> 3) ^ (row & 15)) << 3) + (col & 7)] = ov;
          }

      __syncthreads();   // RAW: sb (lk tile) visible to all waves

      // ---- Su += t1 @ lk^T over j (128 = 4 chunks of 32) ----
#pragma unroll
      for (int ks = 0; ks < 4; ++ks) {
        int ck = ks * 4 + q;
        f16x8 af[2], bf[8];
#pragma unroll
        for (int tr = 0; tr < 2; ++tr)
          af[tr] = *(const f16x8*)(sa + ((w * 32 + tr * 16 + c) << 7) + ((ck ^ c) << 3));
#pragma unroll
        for (int tc = 0; tc < 8; ++tc)
          bf[tc] = *(const f16x8*)(sb + ((tc * 16 + c) << 7) + ((ck ^ c) << 3));
#pragma unroll
        for (int tr = 0; tr < 2; ++tr)
#pragma unroll
          for (int tc = 0; tc < 8; ++tc)
            su[tr][tc] = __builtin_amdgcn_mfma_f32_16x16x32_f16(af[tr], bf[tc], su[tr][tc], 0, 0, 0);
      }
    }

    // scores = Sc - silu(Su): su = -silu(su), then MFMA adds Sc on top
#pragma unroll
    for (int tr = 0; tr < 2; ++tr)
#pragma unroll
      for (int tc = 0; tc < 8; ++tc)
#pragma unroll
        for (int r = 0; r < 4; ++r) {
          float v = su[tr][tc][r];
          su[tr][tc][r] = -(v / (1.f + __expf(-v)));
        }
#pragma unroll
    for (int ks = 0; ks < 2; ++ks) {
      f16x8 bk[8];
#pragma unroll
      for (int tc = 0; tc < 8; ++tc)
        bk[tc] = *(const f16x8*)(kc + (size_t)(K * 128 + tc * 16 + c) * DH + ks * 32 + q * 8);
#pragma unroll
      for (int tr = 0; tr < 2; ++tr)
#pragma unroll
        for (int tc = 0; tc < 8; ++tc)
          su[tr][tc] = __builtin_amdgcn_mfma_f32_16x16x32_f16(a_qc[tr][ks], bk[tc], su[tr][tc], 0, 0, 0);
    }
    if (K == I) {   // strict causal mask inside the diagonal block
#pragma unroll
      for (int tr = 0; tr < 2; ++tr)
#pragma unroll
        for (int tc = 0; tc < 8; ++tc)
#pragma unroll
          for (int r = 0; r < 4; ++r) {
            int rg = w * 32 + tr * 16 + q * 4 + r;
            int cg = tc * 16 + c;
            if (cg > rg) su[tr][tc][r] = -INFINITY;
          }
    }
    // online softmax (row owned by lanes sharing q; reduce across low-4 lane bits)
#pragma unroll
    for (int tr = 0; tr < 2; ++tr)
#pragma unroll
      for (int r = 0; r < 4; ++r) {
        float mx = su[tr][0][r];
#pragma unroll
        for (int tc = 1; tc < 8; ++tc) mx = fmaxf(mx, su[tr][tc][r]);
        mx = fmaxf(mx, __shfl_xor(mx, 1)); mx = fmaxf(mx, __shfl_xor(mx, 2));
        mx = fmaxf(mx, __shfl_xor(mx, 4)); mx = fmaxf(mx, __shfl_xor(mx, 8));
        float mnew  = fmaxf(m_i[tr][r], mx);
        float alpha = __expf(m_i[tr][r] - mnew);
        float s = 0.f;
#pragma unroll
        for (int tc = 0; tc < 8; ++tc) {
          float pp = __expf(su[tr][tc][r] - mnew);
          su[tr][tc][r] = pp;
          s += pp;
        }
        s += __shfl_xor(s, 1); s += __shfl_xor(s, 2); s += __shfl_xor(s, 4); s += __shfl_xor(s, 8);
        l_i[tr][r] = l_i[tr][r] * alpha + s;
        m_i[tr][r] = mnew;
#pragma unroll
        for (int tv = 0; tv < 4; ++tv) oacc[tr][tv][r] *= alpha;
      }
    // write P into sa (own rows only -> no barrier; other waves never read these rows)
#pragma unroll
    for (int tr = 0; tr < 2; ++tr)
#pragma unroll
      for (int tc = 0; tc < 8; ++tc)
#pragma unroll
        for (int r = 0; r < 4; ++r) {
          int row = w * 32 + tr * 16 + q * 4 + r;
          int col = tc * 16 + c;
          sa[(row << 7) + (((col >> 3) ^ (row & 15)) << 3) + (col & 7)] = (f16)su[tr][tc][r];
        }
    // PV: A = P (own LDS rows), B = vcT straight from global (L2-resident)
#pragma unroll
    for (int ks = 0; ks < 4; ++ks) {
      int ck = ks * 4 + q;
      f16x8 af[2], bv[4];
#pragma unroll
      for (int tr = 0; tr < 2; ++tr)
        af[tr] = *(const f16x8*)(sa + ((w * 32 + tr * 16 + c) << 7) + ((ck ^ c) << 3));
#pragma unroll
      for (int tv = 0; tv < 4; ++tv)
        bv[tv] = *(const f16x8*)(vt + (size_t)(tv * 16 + c) * SEQ + K * 128 + ks * 32 + q * 8);
#pragma unroll
      for (int tr = 0; tr < 2; ++tr)
#pragma unroll
        for (int tv = 0; tv < 4; ++tv)
          oacc[tr][tv] = __builtin_amdgcn_mfma_f32_16x16x32_f16(af[tr], bv[tv], oacc[tr][tv], 0, 0, 0);
    }
  }
  // epilogue: O /= l ; out_heads row-major [seq][head*64+dh]
#pragma unroll
  for (int tr = 0; tr < 2; ++tr)
#pragma unroll
    for (int tv = 0; tv < 4; ++tv)
#pragma unroll
      for (int r = 0; r < 4; ++r) {
        int row = I * 128 + w * 32 + tr * 16 + q * 4 + r;
        int col = head * 64 + tv * 16 + c;
        oh[(size_t)row * DIM + col] = (f16)(oacc[tr][tv][r] / l_i[tr][r]);
      }
}

// ---------------- final GEMM: oh[2048,1024] @ WoT[1024,1024]^T -> fp32 out ----------------
__global__ __launch_bounds__(256) void k_gemm_out(const f16* __restrict__ A, const f16* __restrict__ B,
                                                  float* __restrict__ out) {
  __shared__ f16 sa[128 * 72];
  __shared__ f16 sb[128 * 72];
  int bx = blockIdx.x, by = blockIdx.y;
  int tid = threadIdx.x, w = tid >> 6, l = tid & 63, q = l >> 4, c = l & 15;
  f32x4 acc[2][8];
  const f32x4 zf = {0.f, 0.f, 0.f, 0.f};
  for (int i = 0; i < 2; ++i) for (int j = 0; j < 8; ++j) acc[i][j] = zf;
  for (int kt = 0; kt < DIM / 64; ++kt) {
    __syncthreads();
#pragma unroll
    for (int it = 0; it < 4; ++it) {
      int idx = it * 256 + tid; int r = idx >> 3, ch = idx & 7;
      *(float4*)(sa + r * 72 + ch * 8) = *(const float4*)(A + (size_t)(by * 128 + r) * DIM + kt * 64 + ch * 8);
      *(float4*)(sb + r * 72 + ch * 8) = *(const float4*)(B + (size_t)(bx * 128 + r) * DIM + kt * 64 + ch * 8);
    }
    __syncthreads();
#pragma unroll
    for (int ks = 0; ks < 2; ++ks) {
      f16x8 af[2], bf[8];
#pragma unroll
      for (int tr = 0; tr < 2; ++tr) af[tr] = *(const f16x8*)(sa + (w * 32 + tr * 16 + c) * 72 + ks * 32 + q * 8);
#pragma unroll
      for (int tc = 0; tc < 8; ++tc) bf[tc] = *(const f16x8*)(sb + (tc * 16 + c) * 72 + ks * 32 + q * 8);
#pragma unroll
      for (int tr = 0; tr < 2; ++tr)
#pragma unroll
        for (int tc = 0; tc < 8; ++tc)
          acc[tr][tc] = __builtin_amdgcn_mfma_f32_16x16x32_f16(af[tr], bf[tc], acc[tr][tc], 0, 0, 0);
    }
  }
#pragma unroll
  for (int tr = 0; tr < 2; ++tr)
#pragma unroll
    for (int tc = 0; tc < 8; ++tc)
#pragma unroll
      for (int r = 0; r < 4; ++r) {
        int row = by * 128 + w * 32 + tr * 16 + q * 4 + r;
        int col = bx * 128 + tc * 16 + c;
        out[(size_t)row * DIM + col] = acc[tr][tc][r];
      }
}

extern "C" void kernel_launch(void* const* d_in, const int* in_sizes, int n_in,
                              void* d_out, int out_size, void* d_ws, size_t ws_size,
                              hipStream_t stream) {
  const float* x  = (const float*)d_in[0];
  const float* Wq = (const float*)d_in[1];
  const float* Wo = (const float*)d_in[2];
  float* out = (float*)d_out;

  f16* ws = (f16*)d_ws;
  size_t off = 0;
  f16* q6  = ws + off; off += (size_t)6 * NHSD;          // 25.2 MB
  f16* xh  = ws + off; off += (size_t)SEQ * DIM;         // 4 MB
  f16* WqT = ws + off; off += (size_t)NCOLS * DIM;       // 12.6 MB
  f16* WoT = ws + off; off += (size_t)DIM * DIM;         // 2 MB
  f16* oh  = ws + off; off += (size_t)SEQ * DIM;         // 4 MB
  // total ~46 MB of workspace (t1/lk no longer materialized)

  k_cast_x<<<(SEQ * DIM) / 1024, 256, 0, stream>>>(x, xh);
  k_tcast<<<dim3(NCOLS / 64, DIM / 64), 256, 0, stream>>>(Wq, WqT, DIM, NCOLS);
  k_tcast<<<dim3(DIM / 64, DIM / 64), 256, 0, stream>>>(Wo, WoT, DIM, DIM);
  k_gemm_qkv<<<dim3(NCOLS / 128, SEQ / 128), 256, 0, stream>>>(xh, WqT, q6);
  k_flash<<<NH * (SEQ / 128), 256, 0, stream>>>(q6, oh);
  k_gemm_out<<<dim3(DIM / 128, SEQ / 128), 256, 0, stream>>>(oh, WoT, out);
}